// Round 1
// baseline (473.140 us; speedup 1.0000x reference)
//
#include <hip/hip_runtime.h>
#include <math.h>

#define NEG_INF_F (-1e30f)
#define LRELU 0.2f

constexpr int Bb = 64, Ee = 512, IND = 1024, OUTD = 256;
constexpr int Mrows = Bb * Ee; // 32768

// ---------------- Kernel 1: H = X @ W^T + b ----------------
// X: [M][IND] row-major, W: [OUTD][IND] row-major, H: [M][OUTD]
// 64x64 tile, BK=32, 256 threads, 4x4 microtile.
__global__ __launch_bounds__(256) void gemm_h_kernel(
    const float* __restrict__ X, const float* __restrict__ W,
    const float* __restrict__ Wb, float* __restrict__ H)
{
    __shared__ float Xs[32][65]; // [k][m], +1 pad breaks transposed-store conflicts
    __shared__ float Ws[32][65]; // [k][n]

    const int tid = threadIdx.x;
    const int m0 = blockIdx.x * 64;
    const int n0 = blockIdx.y * 64;
    const int tx = tid & 15, ty = tid >> 4;

    float acc[4][4] = {};

    for (int k0 = 0; k0 < IND; k0 += 32) {
        #pragma unroll
        for (int h2 = 0; h2 < 2; ++h2) {
            const int f = h2 * 1024 + 4 * tid; // flat in 64x32 tile
            const int r = f >> 5;              // row in tile, 0..63
            const int k = f & 31;              // k offset, multiple of 4
            const float4 xv = *reinterpret_cast<const float4*>(&X[(size_t)(m0 + r) * IND + k0 + k]);
            Xs[k + 0][r] = xv.x; Xs[k + 1][r] = xv.y; Xs[k + 2][r] = xv.z; Xs[k + 3][r] = xv.w;
            const float4 wv = *reinterpret_cast<const float4*>(&W[(size_t)(n0 + r) * IND + k0 + k]);
            Ws[k + 0][r] = wv.x; Ws[k + 1][r] = wv.y; Ws[k + 2][r] = wv.z; Ws[k + 3][r] = wv.w;
        }
        __syncthreads();
        #pragma unroll
        for (int kk = 0; kk < 32; ++kk) {
            float xa[4], wb[4];
            #pragma unroll
            for (int i = 0; i < 4; ++i) xa[i] = Xs[kk][ty * 4 + i];
            #pragma unroll
            for (int j = 0; j < 4; ++j) wb[j] = Ws[kk][tx * 4 + j];
            #pragma unroll
            for (int i = 0; i < 4; ++i)
                #pragma unroll
                for (int j = 0; j < 4; ++j)
                    acc[i][j] += xa[i] * wb[j];
        }
        __syncthreads();
    }

    #pragma unroll
    for (int i = 0; i < 4; ++i) {
        const int m = m0 + ty * 4 + i;
        float4 o;
        o.x = acc[i][0] + Wb[n0 + tx * 4 + 0];
        o.y = acc[i][1] + Wb[n0 + tx * 4 + 1];
        o.z = acc[i][2] + Wb[n0 + tx * 4 + 2];
        o.w = acc[i][3] + Wb[n0 + tx * 4 + 3];
        *reinterpret_cast<float4*>(&H[(size_t)m * OUTD + n0 + tx * 4]) = o;
    }
}

// ---------------- Kernel 2: s1/s2 row dots ----------------
// s1[m] = sum_o H[m][o]*aw[o];  s2[m] = sum_o H[m][o]*aw[256+o]
__global__ __launch_bounds__(256) void s12_kernel(
    const float* __restrict__ H, const float* __restrict__ aw,
    float* __restrict__ s1, float* __restrict__ s2)
{
    const int row = blockIdx.x * 4 + (threadIdx.x >> 6);
    const int lane = threadIdx.x & 63;
    float v1 = 0.f, v2 = 0.f;
    #pragma unroll
    for (int q = 0; q < 4; ++q) {
        const int o = lane + 64 * q;
        const float h = H[(size_t)row * OUTD + o];
        v1 += h * aw[o];
        v2 += h * aw[OUTD + o];
    }
    #pragma unroll
    for (int off = 32; off; off >>= 1) {
        v1 += __shfl_down(v1, off, 64);
        v2 += __shfl_down(v2, off, 64);
    }
    if (lane == 0) { s1[row] = v1; s2[row] = v2; }
}

// ---------------- Kernel 3: out[b] = softmax(scores[b]) @ (H[b]*m) ----------------
// scores[b,i,j] = (m_i*m_j>0) ? lrelu(s1[b,i]+s2[b,j]+a_b) : NEG_INF
// One block per (b, 16-row tile). 256 threads; thread t owns output column o=t.
__global__ __launch_bounds__(256) void attn_kernel(
    const float* __restrict__ H, const float* __restrict__ s1,
    const float* __restrict__ s2, const int* __restrict__ mask,
    const float* __restrict__ ab_ptr, float* __restrict__ Out)
{
    constexpr int TI = 16;
    __shared__ float s2v[Ee];
    __shared__ float mkf[Ee];
    __shared__ float rowc[TI];
    __shared__ int   rowmi[TI];
    __shared__ float rowmax[TI], rowrz[TI];
    __shared__ float pbufT[64][TI]; // [jj][i] so 4 consecutive i read as float4

    const int b  = blockIdx.x;       // 0..63
    const int i0 = blockIdx.y * TI;  // row tile base
    const int t  = threadIdx.x;
    const float ab = ab_ptr[0];

    for (int j = t; j < Ee; j += 256) {
        s2v[j] = s2[b * Ee + j];
        mkf[j] = (float)mask[b * Ee + j];
    }
    if (t < TI) {
        rowc[t]  = s1[b * Ee + i0 + t] + ab;
        rowmi[t] = mask[b * Ee + i0 + t];
    }
    __syncthreads();

    // ---- pass 1: per-row max & sum (online), 16 threads per row ----
    {
        const int i = t >> 4;
        const int sub = t & 15;
        const float c = rowc[i];
        const int  mi = rowmi[i];
        float mmax = -INFINITY;
        float ssum = 0.f;
        for (int j = sub; j < Ee; j += 16) {
            float s;
            if (mi && mkf[j] > 0.f) {
                const float v = c + s2v[j];
                s = (v >= 0.f) ? v : LRELU * v;
            } else s = NEG_INF_F;
            const float mn = fmaxf(mmax, s);
            ssum = ssum * __expf(mmax - mn) + __expf(s - mn);
            mmax = mn;
        }
        #pragma unroll
        for (int off = 1; off < 16; off <<= 1) {
            const float om = __shfl_xor(mmax, off, 64);
            const float os = __shfl_xor(ssum, off, 64);
            const float mn = fmaxf(mmax, om);
            ssum = ssum * __expf(mmax - mn) + os * __expf(om - mn);
            mmax = mn;
        }
        if (sub == 0) { rowmax[i] = mmax; rowrz[i] = 1.f / ssum; }
    }
    __syncthreads();

    // ---- pass 2: accumulate out rows ----
    float acc[TI];
    #pragma unroll
    for (int i = 0; i < TI; ++i) acc[i] = 0.f;
    const int o = t; // output column
    const float* __restrict__ Hb = H + (size_t)b * Ee * OUTD;

    for (int j0 = 0; j0 < Ee; j0 += 64) {
        __syncthreads(); // protect pbufT from previous tile's readers
        #pragma unroll
        for (int q = 0; q < 4; ++q) {
            const int idx = t + 256 * q; // 0..1023
            const int i  = idx & 15;
            const int jj = idx >> 4;     // 0..63
            const int j  = j0 + jj;
            float s;
            if (rowmi[i] && mkf[j] > 0.f) {
                const float v = rowc[i] + s2v[j];
                s = (v >= 0.f) ? v : LRELU * v;
            } else s = NEG_INF_F;
            pbufT[jj][i] = __expf(s - rowmax[i]) * rowrz[i];
        }
        __syncthreads();
        #pragma unroll
        for (int jj = 0; jj < 64; ++jj) {
            const int j = j0 + jj;
            const float hv = Hb[(size_t)j * OUTD + o] * mkf[j];
            const float4* p4 = reinterpret_cast<const float4*>(&pbufT[jj][0]);
            #pragma unroll
            for (int ib = 0; ib < 4; ++ib) {
                const float4 p = p4[ib];
                acc[ib * 4 + 0] += p.x * hv;
                acc[ib * 4 + 1] += p.y * hv;
                acc[ib * 4 + 2] += p.z * hv;
                acc[ib * 4 + 3] += p.w * hv;
            }
        }
    }

    #pragma unroll
    for (int i = 0; i < TI; ++i)
        Out[((size_t)b * Ee + i0 + i) * OUTD + o] = acc[i];
}

extern "C" void kernel_launch(void* const* d_in, const int* in_sizes, int n_in,
                              void* d_out, int out_size, void* d_ws, size_t ws_size,
                              hipStream_t stream) {
    const float* X    = (const float*)d_in[0];
    // d_in[1] = adj : unused by the reference (dead input)
    const int*   mask = (const int*)d_in[2];
    const float* Ww   = (const float*)d_in[3];
    const float* Wb   = (const float*)d_in[4];
    const float* aw   = (const float*)d_in[5];
    const float* ab   = (const float*)d_in[6];
    float* out = (float*)d_out;

    float* H  = (float*)d_ws;                       // 32768*256 floats = 32 MB
    float* s1 = H + (size_t)Mrows * OUTD;           // 32768 floats
    float* s2 = s1 + Mrows;                         // 32768 floats

    gemm_h_kernel<<<dim3(Mrows / 64, OUTD / 64), 256, 0, stream>>>(X, Ww, Wb, H);
    s12_kernel<<<Mrows / 4, 256, 0, stream>>>(H, aw, s1, s2);
    attn_kernel<<<dim3(Bb, Ee / 16), 256, 0, stream>>>(H, s1, s2, mask, ab, out);
}

// Round 2
// 303.969 us; speedup vs baseline: 1.5565x; 1.5565x over previous
//
#include <hip/hip_runtime.h>
#include <hip/hip_fp16.h>
#include <math.h>

#define NEG_INF_F (-1e30f)
#define LRELU 0.2f

constexpr int Bb = 64, Ee = 512, IND = 1024, OUTD = 256;
constexpr int Mrows = Bb * Ee; // 32768

typedef __attribute__((ext_vector_type(8))) _Float16 half8;
typedef __attribute__((ext_vector_type(4))) _Float16 half4;
typedef __attribute__((ext_vector_type(4))) float floatx4;

// ---------------- Kernel 0: split W into fp16 hi/lo ----------------
__global__ __launch_bounds__(256) void wconv_kernel(
    const float* __restrict__ W, _Float16* __restrict__ Whi, _Float16* __restrict__ Wlo)
{
    const int i = (blockIdx.x * 256 + threadIdx.x) * 4;
    const float4 w = *reinterpret_cast<const float4*>(&W[i]);
    half4 hh, hl;
    hh[0] = (_Float16)w.x; hl[0] = (_Float16)(w.x - (float)hh[0]);
    hh[1] = (_Float16)w.y; hl[1] = (_Float16)(w.y - (float)hh[1]);
    hh[2] = (_Float16)w.z; hl[2] = (_Float16)(w.z - (float)hh[2]);
    hh[3] = (_Float16)w.w; hl[3] = (_Float16)(w.w - (float)hh[3]);
    *reinterpret_cast<half4*>(&Whi[i]) = hh;
    *reinterpret_cast<half4*>(&Wlo[i]) = hl;
}

// ---------------- Kernel 1: H = X @ W^T + b via fp16 MFMA (2-term split) ----
// X: [M][1024] fp32.  Whi/Wlo: [256][1024] fp16.  H: [M][256] fp32.
// Block: 256 thr = 4 waves. Tile BM=64 x BN=256, BK=32.
// Wave w owns output cols [w*64, w*64+64) of all 64 rows.
// Also emits s1[m] = H[m]·aw[0:256], s2[m] = H[m]·aw[256:512] (fused epilogue).
__global__ __launch_bounds__(256) void gemm_h_f16(
    const float* __restrict__ X, const _Float16* __restrict__ Whi,
    const _Float16* __restrict__ Wlo, const float* __restrict__ Wb,
    const float* __restrict__ aw, float* __restrict__ H,
    float* __restrict__ s1, float* __restrict__ s2)
{
    __shared__ _Float16 As[4][64][8];   // [kgroup][m][8]
    __shared__ _Float16 Bh[4][256][8];  // [kgroup][n][8]
    __shared__ _Float16 Bl[4][256][8];
    __shared__ float s1p[4][64], s2p[4][64];

    const int t  = threadIdx.x;
    const int w  = t >> 6;       // wave 0..3
    const int l  = t & 63;       // lane
    const int ln = l & 15;       // frag col/row-group index
    const int lg = l >> 4;       // k-group 0..3
    const int m0 = blockIdx.x * 64;

    // A-staging assignment: thread t -> row ar, k-subgroup akg (coalesced X read)
    const int ar = t >> 2, akg = t & 3;
    const float* __restrict__ xrow = X + (size_t)(m0 + ar) * IND + akg * 8;

    floatx4 acc[4][4];
    #pragma unroll
    for (int i = 0; i < 4; ++i)
        #pragma unroll
        for (int j = 0; j < 4; ++j)
            acc[i][j] = (floatx4)0.f;

    const size_t bro = (size_t)(w * 64 + l) * IND; // B global row offset (halves)

    #pragma unroll 2
    for (int k0 = 0; k0 < IND; k0 += 32) {
        __syncthreads(); // previous tile fully consumed

        // ---- stage A: fp32 -> fp16 convert, ds_write_b128 ----
        const float4 x0 = *reinterpret_cast<const float4*>(xrow + k0);
        const float4 x1 = *reinterpret_cast<const float4*>(xrow + k0 + 4);
        half8 ah;
        ah[0] = (_Float16)x0.x; ah[1] = (_Float16)x0.y;
        ah[2] = (_Float16)x0.z; ah[3] = (_Float16)x0.w;
        ah[4] = (_Float16)x1.x; ah[5] = (_Float16)x1.y;
        ah[6] = (_Float16)x1.z; ah[7] = (_Float16)x1.w;
        *reinterpret_cast<half8*>(&As[akg][ar][0]) = ah;

        // ---- stage B: global_load_lds width 16, wave-private n-slice ----
        #pragma unroll
        for (int kg = 0; kg < 4; ++kg) {
            __builtin_amdgcn_global_load_lds(
                (const __attribute__((address_space(1))) unsigned int*)(Whi + bro + k0 + kg * 8),
                (__attribute__((address_space(3))) unsigned int*)&Bh[kg][w * 64][0],
                16, 0, 0);
            __builtin_amdgcn_global_load_lds(
                (const __attribute__((address_space(1))) unsigned int*)(Wlo + bro + k0 + kg * 8),
                (__attribute__((address_space(3))) unsigned int*)&Bl[kg][w * 64][0],
                16, 0, 0);
        }
        __syncthreads(); // staging complete (vmcnt(0)+lgkmcnt(0) drained by barrier)

        // ---- compute: 32 MFMAs ----
        half8 a[4], bh[4], bl[4];
        #pragma unroll
        for (int mrep = 0; mrep < 4; ++mrep)
            a[mrep] = *reinterpret_cast<const half8*>(&As[lg][mrep * 16 + ln][0]);
        #pragma unroll
        for (int nrep = 0; nrep < 4; ++nrep) {
            bh[nrep] = *reinterpret_cast<const half8*>(&Bh[lg][w * 64 + nrep * 16 + ln][0]);
            bl[nrep] = *reinterpret_cast<const half8*>(&Bl[lg][w * 64 + nrep * 16 + ln][0]);
        }
        #pragma unroll
        for (int mrep = 0; mrep < 4; ++mrep)
            #pragma unroll
            for (int nrep = 0; nrep < 4; ++nrep) {
                acc[mrep][nrep] = __builtin_amdgcn_mfma_f32_16x16x32_f16(
                    a[mrep], bh[nrep], acc[mrep][nrep], 0, 0, 0);
                acc[mrep][nrep] = __builtin_amdgcn_mfma_f32_16x16x32_f16(
                    a[mrep], bl[nrep], acc[mrep][nrep], 0, 0, 0);
            }
    }

    // ---- epilogue: bias, H store, fused s1/s2 ----
    float bias[4], a1c[4], a2c[4];
    #pragma unroll
    for (int nrep = 0; nrep < 4; ++nrep) {
        const int n = w * 64 + nrep * 16 + ln;
        bias[nrep] = Wb[n];
        a1c[nrep]  = aw[n];
        a2c[nrep]  = aw[OUTD + n];
    }
    float sv1[4][4], sv2[4][4];
    #pragma unroll
    for (int i = 0; i < 4; ++i)
        #pragma unroll
        for (int r = 0; r < 4; ++r) { sv1[i][r] = 0.f; sv2[i][r] = 0.f; }

    #pragma unroll
    for (int mrep = 0; mrep < 4; ++mrep)
        #pragma unroll
        for (int nrep = 0; nrep < 4; ++nrep) {
            #pragma unroll
            for (int rr = 0; rr < 4; ++rr) {
                const float hb = acc[mrep][nrep][rr] + bias[nrep];
                const int m = m0 + mrep * 16 + lg * 4 + rr;
                H[(size_t)m * OUTD + w * 64 + nrep * 16 + ln] = hb;
                sv1[mrep][rr] += hb * a1c[nrep];
                sv2[mrep][rr] += hb * a2c[nrep];
            }
        }

    #pragma unroll
    for (int mrep = 0; mrep < 4; ++mrep)
        #pragma unroll
        for (int rr = 0; rr < 4; ++rr) {
            float v1 = sv1[mrep][rr], v2 = sv2[mrep][rr];
            #pragma unroll
            for (int off = 1; off < 16; off <<= 1) {
                v1 += __shfl_xor(v1, off, 64);
                v2 += __shfl_xor(v2, off, 64);
            }
            if (ln == 0) {
                s1p[w][mrep * 16 + lg * 4 + rr] = v1;
                s2p[w][mrep * 16 + lg * 4 + rr] = v2;
            }
        }
    __syncthreads();
    if (t < 64) {
        s1[m0 + t] = s1p[0][t] + s1p[1][t] + s1p[2][t] + s1p[3][t];
        s2[m0 + t] = s2p[0][t] + s2p[1][t] + s2p[2][t] + s2p[3][t];
    }
}

// ---------------- Kernel 3: out[b] = softmax(scores[b]) @ (H[b]*m) ----------------
__global__ __launch_bounds__(256) void attn_kernel(
    const float* __restrict__ H, const float* __restrict__ s1,
    const float* __restrict__ s2, const int* __restrict__ mask,
    const float* __restrict__ ab_ptr, float* __restrict__ Out)
{
    constexpr int TI = 16;
    __shared__ float s2v[Ee];
    __shared__ float mkf[Ee];
    __shared__ float rowc[TI];
    __shared__ int   rowmi[TI];
    __shared__ float rowmax[TI], rowrz[TI];
    __shared__ float pbufT[64][TI];

    const int b  = blockIdx.x;
    const int i0 = blockIdx.y * TI;
    const int t  = threadIdx.x;
    const float ab = ab_ptr[0];

    for (int j = t; j < Ee; j += 256) {
        s2v[j] = s2[b * Ee + j];
        mkf[j] = (float)mask[b * Ee + j];
    }
    if (t < TI) {
        rowc[t]  = s1[b * Ee + i0 + t] + ab;
        rowmi[t] = mask[b * Ee + i0 + t];
    }
    __syncthreads();

    {
        const int i = t >> 4;
        const int sub = t & 15;
        const float c = rowc[i];
        const int  mi = rowmi[i];
        float mmax = -INFINITY;
        float ssum = 0.f;
        for (int j = sub; j < Ee; j += 16) {
            float s;
            if (mi && mkf[j] > 0.f) {
                const float v = c + s2v[j];
                s = (v >= 0.f) ? v : LRELU * v;
            } else s = NEG_INF_F;
            const float mn = fmaxf(mmax, s);
            ssum = ssum * __expf(mmax - mn) + __expf(s - mn);
            mmax = mn;
        }
        #pragma unroll
        for (int off = 1; off < 16; off <<= 1) {
            const float om = __shfl_xor(mmax, off, 64);
            const float os = __shfl_xor(ssum, off, 64);
            const float mn = fmaxf(mmax, om);
            ssum = ssum * __expf(mmax - mn) + os * __expf(om - mn);
            mmax = mn;
        }
        if (sub == 0) { rowmax[i] = mmax; rowrz[i] = 1.f / ssum; }
    }
    __syncthreads();

    float acc[TI];
    #pragma unroll
    for (int i = 0; i < TI; ++i) acc[i] = 0.f;
    const int o = t;
    const float* __restrict__ Hb = H + (size_t)b * Ee * OUTD;

    for (int j0 = 0; j0 < Ee; j0 += 64) {
        __syncthreads();
        #pragma unroll
        for (int q = 0; q < 4; ++q) {
            const int idx = t + 256 * q;
            const int i  = idx & 15;
            const int jj = idx >> 4;
            const int j  = j0 + jj;
            float s;
            if (rowmi[i] && mkf[j] > 0.f) {
                const float v = rowc[i] + s2v[j];
                s = (v >= 0.f) ? v : LRELU * v;
            } else s = NEG_INF_F;
            pbufT[jj][i] = __expf(s - rowmax[i]) * rowrz[i];
        }
        __syncthreads();
        #pragma unroll
        for (int jj = 0; jj < 64; ++jj) {
            const int j = j0 + jj;
            const float hv = Hb[(size_t)j * OUTD + o] * mkf[j];
            const float4* p4 = reinterpret_cast<const float4*>(&pbufT[jj][0]);
            #pragma unroll
            for (int ib = 0; ib < 4; ++ib) {
                const float4 p = p4[ib];
                acc[ib * 4 + 0] += p.x * hv;
                acc[ib * 4 + 1] += p.y * hv;
                acc[ib * 4 + 2] += p.z * hv;
                acc[ib * 4 + 3] += p.w * hv;
            }
        }
    }

    #pragma unroll
    for (int i = 0; i < TI; ++i)
        Out[((size_t)b * Ee + i0 + i) * OUTD + o] = acc[i];
}

extern "C" void kernel_launch(void* const* d_in, const int* in_sizes, int n_in,
                              void* d_out, int out_size, void* d_ws, size_t ws_size,
                              hipStream_t stream) {
    const float* X    = (const float*)d_in[0];
    // d_in[1] = adj : unused by the reference (dead input)
    const int*   mask = (const int*)d_in[2];
    const float* Ww   = (const float*)d_in[3];
    const float* Wb   = (const float*)d_in[4];
    const float* aw   = (const float*)d_in[5];
    const float* ab   = (const float*)d_in[6];
    float* out = (float*)d_out;

    float* H  = (float*)d_ws;                         // 32768*256 f32 = 32 MB
    float* s1 = H + (size_t)Mrows * OUTD;             // 32768 f32
    float* s2 = s1 + Mrows;                           // 32768 f32
    _Float16* Whi = (_Float16*)(s2 + Mrows);          // 256*1024 fp16 = 512 KB
    _Float16* Wlo = Whi + (size_t)OUTD * IND;         // 512 KB

    wconv_kernel<<<OUTD * IND / (256 * 4), 256, 0, stream>>>(Ww, Whi, Wlo);
    gemm_h_f16<<<Mrows / 64, 256, 0, stream>>>(X, Whi, Wlo, Wb, aw, H, s1, s2);
    attn_kernel<<<dim3(Bb, Ee / 16), 256, 0, stream>>>(H, s1, s2, mask, ab, out);
}

// Round 3
// 196.137 us; speedup vs baseline: 2.4123x; 1.5498x over previous
//
#include <hip/hip_runtime.h>
#include <hip/hip_fp16.h>
#include <math.h>

#define NEG_INF_F (-1e30f)
#define LRELU 0.2f

constexpr int Bb = 64, Ee = 512, IND = 1024, OUTD = 256;
constexpr int Mrows = Bb * Ee; // 32768

typedef __attribute__((ext_vector_type(8))) _Float16 half8;
typedef __attribute__((ext_vector_type(4))) _Float16 half4;
typedef __attribute__((ext_vector_type(4))) float floatx4;

// ---------------- Kernel 0: split W into fp16 hi/lo ----------------
__global__ __launch_bounds__(256) void wconv_kernel(
    const float* __restrict__ W, _Float16* __restrict__ Whi, _Float16* __restrict__ Wlo)
{
    const int i = (blockIdx.x * 256 + threadIdx.x) * 4;
    const float4 w = *reinterpret_cast<const float4*>(&W[i]);
    half4 hh, hl;
    hh[0] = (_Float16)w.x; hl[0] = (_Float16)(w.x - (float)hh[0]);
    hh[1] = (_Float16)w.y; hl[1] = (_Float16)(w.y - (float)hh[1]);
    hh[2] = (_Float16)w.z; hl[2] = (_Float16)(w.z - (float)hh[2]);
    hh[3] = (_Float16)w.w; hl[3] = (_Float16)(w.w - (float)hh[3]);
    *reinterpret_cast<half4*>(&Whi[i]) = hh;
    *reinterpret_cast<half4*>(&Wlo[i]) = hl;
}

// ---------------- Kernel 1: H = X @ W^T + b via fp16 MFMA (2-term split) ----
// Emits: HmT_hi/lo[b][o][e] = fp16 split of (H*mask)  (transposed per batch),
//        s1[m], s2[m] (fused epilogue). No fp32 H is materialized.
__global__ __launch_bounds__(256) void gemm_h_f16(
    const float* __restrict__ X, const _Float16* __restrict__ Whi,
    const _Float16* __restrict__ Wlo, const float* __restrict__ Wb,
    const float* __restrict__ aw, const int* __restrict__ mask,
    _Float16* __restrict__ HmTh, _Float16* __restrict__ HmTl,
    float* __restrict__ s1, float* __restrict__ s2)
{
    __shared__ _Float16 As[4][64][8];   // [kgroup][m][8]
    __shared__ _Float16 Bh[4][256][8];  // [kgroup][n][8]
    __shared__ _Float16 Bl[4][256][8];
    __shared__ float s1p[4][64], s2p[4][64];
    __shared__ float mkf[64];

    const int t  = threadIdx.x;
    const int w  = t >> 6;       // wave 0..3
    const int l  = t & 63;       // lane
    const int ln = l & 15;
    const int lg = l >> 4;
    const int m0 = blockIdx.x * 64;

    if (t < 64) mkf[t] = (float)mask[m0 + t];

    const int ar = t >> 2, akg = t & 3;
    const float* __restrict__ xrow = X + (size_t)(m0 + ar) * IND + akg * 8;

    floatx4 acc[4][4];
    #pragma unroll
    for (int i = 0; i < 4; ++i)
        #pragma unroll
        for (int j = 0; j < 4; ++j)
            acc[i][j] = (floatx4)0.f;

    const size_t bro = (size_t)(w * 64 + l) * IND;

    #pragma unroll 2
    for (int k0 = 0; k0 < IND; k0 += 32) {
        __syncthreads();

        const float4 x0 = *reinterpret_cast<const float4*>(xrow + k0);
        const float4 x1 = *reinterpret_cast<const float4*>(xrow + k0 + 4);
        half8 ah;
        ah[0] = (_Float16)x0.x; ah[1] = (_Float16)x0.y;
        ah[2] = (_Float16)x0.z; ah[3] = (_Float16)x0.w;
        ah[4] = (_Float16)x1.x; ah[5] = (_Float16)x1.y;
        ah[6] = (_Float16)x1.z; ah[7] = (_Float16)x1.w;
        *reinterpret_cast<half8*>(&As[akg][ar][0]) = ah;

        #pragma unroll
        for (int kg = 0; kg < 4; ++kg) {
            __builtin_amdgcn_global_load_lds(
                (const __attribute__((address_space(1))) unsigned int*)(Whi + bro + k0 + kg * 8),
                (__attribute__((address_space(3))) unsigned int*)&Bh[kg][w * 64][0],
                16, 0, 0);
            __builtin_amdgcn_global_load_lds(
                (const __attribute__((address_space(1))) unsigned int*)(Wlo + bro + k0 + kg * 8),
                (__attribute__((address_space(3))) unsigned int*)&Bl[kg][w * 64][0],
                16, 0, 0);
        }
        __syncthreads();

        half8 a[4], bh[4], bl[4];
        #pragma unroll
        for (int mrep = 0; mrep < 4; ++mrep)
            a[mrep] = *reinterpret_cast<const half8*>(&As[lg][mrep * 16 + ln][0]);
        #pragma unroll
        for (int nrep = 0; nrep < 4; ++nrep) {
            bh[nrep] = *reinterpret_cast<const half8*>(&Bh[lg][w * 64 + nrep * 16 + ln][0]);
            bl[nrep] = *reinterpret_cast<const half8*>(&Bl[lg][w * 64 + nrep * 16 + ln][0]);
        }
        #pragma unroll
        for (int mrep = 0; mrep < 4; ++mrep)
            #pragma unroll
            for (int nrep = 0; nrep < 4; ++nrep) {
                acc[mrep][nrep] = __builtin_amdgcn_mfma_f32_16x16x32_f16(
                    a[mrep], bh[nrep], acc[mrep][nrep], 0, 0, 0);
                acc[mrep][nrep] = __builtin_amdgcn_mfma_f32_16x16x32_f16(
                    a[mrep], bl[nrep], acc[mrep][nrep], 0, 0, 0);
            }
    }

    // ---- epilogue: bias, masked fp16 hi/lo transposed store, fused s1/s2 ----
    float bias[4], a1c[4], a2c[4];
    #pragma unroll
    for (int nrep = 0; nrep < 4; ++nrep) {
        const int n = w * 64 + nrep * 16 + ln;
        bias[nrep] = Wb[n];
        a1c[nrep]  = aw[n];
        a2c[nrep]  = aw[OUTD + n];
    }
    float sv1[4][4], sv2[4][4];
    #pragma unroll
    for (int i = 0; i < 4; ++i)
        #pragma unroll
        for (int r = 0; r < 4; ++r) { sv1[i][r] = 0.f; sv2[i][r] = 0.f; }

    const int bIdx = m0 >> 9;       // batch
    const int e0   = m0 & 511;      // e base within batch

    #pragma unroll
    for (int mrep = 0; mrep < 4; ++mrep)
        #pragma unroll
        for (int nrep = 0; nrep < 4; ++nrep) {
            const int n = w * 64 + nrep * 16 + ln;
            half4 hh, hl;
            #pragma unroll
            for (int rr = 0; rr < 4; ++rr) {
                const float hb = acc[mrep][nrep][rr] + bias[nrep];
                sv1[mrep][rr] += hb * a1c[nrep];
                sv2[mrep][rr] += hb * a2c[nrep];
                const float hm = hb * mkf[mrep * 16 + lg * 4 + rr];
                const _Float16 hhi = (_Float16)hm;
                hh[rr] = hhi;
                hl[rr] = (_Float16)(hm - (float)hhi);
            }
            const size_t off = ((size_t)(bIdx * OUTD + n) << 9) + e0 + mrep * 16 + lg * 4;
            *reinterpret_cast<half4*>(&HmTh[off]) = hh;
            *reinterpret_cast<half4*>(&HmTl[off]) = hl;
        }

    #pragma unroll
    for (int mrep = 0; mrep < 4; ++mrep)
        #pragma unroll
        for (int rr = 0; rr < 4; ++rr) {
            float v1 = sv1[mrep][rr], v2 = sv2[mrep][rr];
            #pragma unroll
            for (int off = 1; off < 16; off <<= 1) {
                v1 += __shfl_xor(v1, off, 64);
                v2 += __shfl_xor(v2, off, 64);
            }
            if (ln == 0) {
                s1p[w][mrep * 16 + lg * 4 + rr] = v1;
                s2p[w][mrep * 16 + lg * 4 + rr] = v2;
            }
        }
    __syncthreads();
    if (t < 64) {
        s1[m0 + t] = s1p[0][t] + s1p[1][t] + s1p[2][t] + s1p[3][t];
        s2[m0 + t] = s2p[0][t] + s2p[1][t] + s2p[2][t] + s2p[3][t];
    }
}

// ---------------- Kernel 2: out[b] = softmax(scores[b]) @ (H[b]*m), MFMA ----
// Single-pass: rowmax known analytically (lrelu monotone + rank-1 scores).
// Block = (batch b, 64-row i-tile). 4 waves, wave w owns out cols [w*64, w*64+64).
__global__ __launch_bounds__(256, 2) void attn_mfma(
    const _Float16* __restrict__ HmTh, const _Float16* __restrict__ HmTl,
    const float* __restrict__ s1, const float* __restrict__ s2,
    const int* __restrict__ mask, const float* __restrict__ ab_ptr,
    float* __restrict__ Out)
{
    __shared__ float s2v[Ee];
    __shared__ float mkv[Ee];
    __shared__ float rowc[64];
    __shared__ float rmax[64];
    __shared__ int   rvv[64];
    __shared__ _Float16 Pl[2][64][32];
    __shared__ float Zp[64][4];
    __shared__ float zr[64];
    __shared__ float wmax[4];

    const int bid = blockIdx.x;
    const int b  = bid & 63;          // same-batch blocks 64 apart -> same XCD
    const int i0 = (bid >> 6) * 64;
    const int t  = threadIdx.x;
    const int w  = t >> 6, l = t & 63, ln = l & 15, lg = l >> 4;
    const float ab = ab_ptr[0];

    // stage s2 + mask, block-reduce masked max(s2)
    float lmax = -INFINITY;
    #pragma unroll
    for (int q = 0; q < 2; ++q) {
        const int j = t + q * 256;
        const float sv = s2[b * Ee + j];
        const float mv = (float)mask[b * Ee + j];
        s2v[j] = sv; mkv[j] = mv;
        if (mv > 0.f) lmax = fmaxf(lmax, sv);
    }
    #pragma unroll
    for (int off = 32; off; off >>= 1) lmax = fmaxf(lmax, __shfl_xor(lmax, off, 64));
    if (l == 0) wmax[w] = lmax;
    __syncthreads();
    const float s2max = fmaxf(fmaxf(wmax[0], wmax[1]), fmaxf(wmax[2], wmax[3]));
    const int anyvalid = (s2max > -1e37f) ? 1 : 0;
    if (t < 64) {
        const float c = s1[b * Ee + i0 + t] + ab;
        rowc[t] = c;
        const int mi = mask[b * Ee + i0 + t];
        rvv[t] = (mi != 0) & anyvalid;
        const float rm = c + s2max;
        rmax[t] = (rm >= 0.f) ? rm : LRELU * rm;
    }
    __syncthreads();

    // P-generation assignment: thread -> (row pi, 8-wide j chunk pj)
    const int pi = t >> 2;
    const int pj = (t & 3) * 8;
    const float prc = rowc[pi];
    const float prm = rmax[pi];
    const int   prv = rvv[pi];
    float zacc = 0.f;

    const size_t obase = (size_t)b * OUTD * Ee;
    const int o0 = w * 64;

    floatx4 acc[4][4];
    #pragma unroll
    for (int i = 0; i < 4; ++i)
        #pragma unroll
        for (int j = 0; j < 4; ++j)
            acc[i][j] = (floatx4)0.f;

    for (int ks = 0; ks < 16; ++ks) {
        const int k0  = ks * 32;
        const int buf = ks & 1;

        // ---- generate unnormalized P tile (fp16), accumulate Z ----
        half8 ph;
        #pragma unroll
        for (int kk = 0; kk < 8; ++kk) {
            const int j = k0 + pj + kk;
            float pv;
            if (prv) {
                float sc = prc + s2v[j];
                sc = (sc >= 0.f) ? sc : LRELU * sc;
                pv = (mkv[j] > 0.f) ? __expf(sc - prm) : 0.f;
            } else {
                pv = 1.f;
            }
            const _Float16 hq = (_Float16)pv;
            ph[kk] = hq;
            zacc += (float)hq;
        }
        *reinterpret_cast<half8*>(&Pl[buf][pi][pj]) = ph;

        // ---- B-fragments straight from global (L2-resident HmT) ----
        half8 bh[4], bl[4];
        #pragma unroll
        for (int ot = 0; ot < 4; ++ot) {
            const size_t ro = obase + (size_t)(o0 + ot * 16 + ln) * Ee + k0 + lg * 8;
            bh[ot] = *reinterpret_cast<const half8*>(&HmTh[ro]);
            bl[ot] = *reinterpret_cast<const half8*>(&HmTl[ro]);
        }
        __syncthreads();

        half8 af[4];
        #pragma unroll
        for (int mr = 0; mr < 4; ++mr)
            af[mr] = *reinterpret_cast<const half8*>(&Pl[buf][mr * 16 + ln][lg * 8]);
        #pragma unroll
        for (int mr = 0; mr < 4; ++mr)
            #pragma unroll
            for (int ot = 0; ot < 4; ++ot) {
                acc[mr][ot] = __builtin_amdgcn_mfma_f32_16x16x32_f16(
                    af[mr], bh[ot], acc[mr][ot], 0, 0, 0);
                acc[mr][ot] = __builtin_amdgcn_mfma_f32_16x16x32_f16(
                    af[mr], bl[ot], acc[mr][ot], 0, 0, 0);
            }
    }

    // ---- normalize & store ----
    Zp[pi][t & 3] = zacc;
    __syncthreads();
    if (t < 64) {
        const float z = Zp[t][0] + Zp[t][1] + Zp[t][2] + Zp[t][3];
        zr[t] = 1.f / z;
    }
    __syncthreads();

    float* __restrict__ Ob = Out + ((size_t)b * Ee + i0) * OUTD;
    #pragma unroll
    for (int mr = 0; mr < 4; ++mr)
        #pragma unroll
        for (int rr = 0; rr < 4; ++rr) {
            const int i = mr * 16 + lg * 4 + rr;
            const float rzi = zr[i];
            #pragma unroll
            for (int ot = 0; ot < 4; ++ot)
                Ob[(size_t)i * OUTD + o0 + ot * 16 + ln] = acc[mr][ot][rr] * rzi;
        }
}

extern "C" void kernel_launch(void* const* d_in, const int* in_sizes, int n_in,
                              void* d_out, int out_size, void* d_ws, size_t ws_size,
                              hipStream_t stream) {
    const float* X    = (const float*)d_in[0];
    // d_in[1] = adj : unused by the reference (dead input)
    const int*   mask = (const int*)d_in[2];
    const float* Ww   = (const float*)d_in[3];
    const float* Wb   = (const float*)d_in[4];
    const float* aw   = (const float*)d_in[5];
    const float* ab   = (const float*)d_in[6];
    float* out = (float*)d_out;

    _Float16* HmTh = (_Float16*)d_ws;                     // [64][256][512] fp16 = 16 MB
    _Float16* HmTl = HmTh + (size_t)Bb * OUTD * Ee;       // 16 MB
    float* s1 = (float*)(HmTl + (size_t)Bb * OUTD * Ee);  // 128 KB
    float* s2 = s1 + Mrows;                               // 128 KB
    _Float16* Whi = (_Float16*)(s2 + Mrows);              // 512 KB
    _Float16* Wlo = Whi + (size_t)OUTD * IND;             // 512 KB

    wconv_kernel<<<OUTD * IND / (256 * 4), 256, 0, stream>>>(Ww, Whi, Wlo);
    gemm_h_f16<<<Mrows / 64, 256, 0, stream>>>(X, Whi, Wlo, Wb, aw, mask,
                                               HmTh, HmTl, s1, s2);
    attn_mfma<<<Bb * (Ee / 64), 256, 0, stream>>>(HmTh, HmTl, s1, s2, mask, ab, out);
}

// Round 4
// 83.253 us; speedup vs baseline: 5.6832x; 2.3559x over previous
//
#include <hip/hip_runtime.h>
#include <hip/hip_fp16.h>
#include <math.h>

#define NEG_INF_F (-1e30f)
#define LRELU 0.2f

constexpr int Bb = 64, Ee = 512, IND = 1024, OUTD = 256;
constexpr int Mrows = Bb * Ee; // 32768

typedef __attribute__((ext_vector_type(8))) _Float16 half8;
typedef __attribute__((ext_vector_type(4))) _Float16 half4;
typedef __attribute__((ext_vector_type(4))) float floatx4;

#define AS1 __attribute__((address_space(1)))
#define AS3 __attribute__((address_space(3)))

// ---------------- Kernel 0: W fp32 -> fp16 (single) ----------------
__global__ __launch_bounds__(256) void wconv_kernel(
    const float* __restrict__ W, _Float16* __restrict__ Whf)
{
    const int i = (blockIdx.x * 256 + threadIdx.x) * 4;
    const float4 w = *reinterpret_cast<const float4*>(&W[i]);
    half4 hh;
    hh[0] = (_Float16)w.x; hh[1] = (_Float16)w.y;
    hh[2] = (_Float16)w.z; hh[3] = (_Float16)w.w;
    *reinterpret_cast<half4*>(&Whf[i]) = hh;
}

// ---------------- Kernel 1: H = X @ W^T + b, 2-phase pipelined fp16 MFMA ----
// BM=64, BN=256(full), BK=64, 4 waves. Double-buffered LDS, XOR-swizzled.
// Emits HmT_hi/lo[b][o][e] (masked, transposed via LDS) + fused s1/s2.
__global__ __launch_bounds__(256) void gemm_h_f16(
    const float* __restrict__ X, const _Float16* __restrict__ Whf,
    const float* __restrict__ Wb, const float* __restrict__ aw,
    const int* __restrict__ mask,
    _Float16* __restrict__ HmTh, _Float16* __restrict__ HmTl,
    float* __restrict__ s1, float* __restrict__ s2)
{
    __shared__ char lds_raw[81920];
    _Float16* As = (_Float16*)lds_raw;             // [2][64][64]   16 KB
    _Float16* Bs = (_Float16*)(lds_raw + 16384);   // [2][256][64]  64 KB
    // epilogue overlays:
    float*    s1p  = (float*)lds_raw;              // [4][64] 1 KB
    float*    s2p  = (float*)(lds_raw + 1024);     // [4][64] 1 KB
    float*    mkfs = (float*)(lds_raw + 2048);     // [64]
    _Float16* Th   = (_Float16*)(lds_raw + 16384); // [256][64] 32 KB
    _Float16* Tl   = (_Float16*)(lds_raw + 49152); // [256][64] 32 KB

    const int t  = threadIdx.x;
    const int w  = t >> 6;       // wave 0..3
    const int l  = t & 63;       // lane
    const int ln = l & 15;
    const int lg = l >> 4;
    const int m0 = blockIdx.x * 64;

    // A staging: thread handles rows mA, mA+32 at k-chunk pp (8 halves)
    const int mA = t >> 3, pp = t & 7;
    const int aswz = pp ^ (mA & 7); // (mA+32)&7 == mA&7
    const float* __restrict__ xbase = X + (size_t)m0 * IND;

    // B staging: per gload_lds j, lane -> n = w*64 + j*8 + bn_sub, src chunk bkg
    const int bn_sub = l >> 3;
    const int bkg = (l & 7) ^ (bn_sub & 7);

    floatx4 acc[4][4];
    #pragma unroll
    for (int i = 0; i < 4; ++i)
        #pragma unroll
        for (int j = 0; j < 4; ++j)
            acc[i][j] = (floatx4)0.f;

    // ---- staging helpers ----
    auto loadA = [&](int k0, float4 xr[2][2]) {
        #pragma unroll
        for (int i = 0; i < 2; ++i) {
            const float* p = xbase + (size_t)(mA + 32 * i) * IND + k0 + pp * 8;
            xr[i][0] = *reinterpret_cast<const float4*>(p);
            xr[i][1] = *reinterpret_cast<const float4*>(p + 4);
        }
    };
    auto writeA = [&](int buf, float4 xr[2][2]) {
        #pragma unroll
        for (int i = 0; i < 2; ++i) {
            half8 h;
            h[0] = (_Float16)xr[i][0].x; h[1] = (_Float16)xr[i][0].y;
            h[2] = (_Float16)xr[i][0].z; h[3] = (_Float16)xr[i][0].w;
            h[4] = (_Float16)xr[i][1].x; h[5] = (_Float16)xr[i][1].y;
            h[6] = (_Float16)xr[i][1].z; h[7] = (_Float16)xr[i][1].w;
            *reinterpret_cast<half8*>(As + buf * 4096 + (mA + 32 * i) * 64 + aswz * 8) = h;
        }
    };
    auto stageB = [&](int buf, int k0) {
        #pragma unroll
        for (int j = 0; j < 8; ++j) {
            const int n = w * 64 + j * 8 + bn_sub;
            __builtin_amdgcn_global_load_lds(
                (const AS1 unsigned int*)(Whf + (size_t)n * IND + k0 + bkg * 8),
                (AS3 unsigned int*)(Bs + buf * 16384 + w * 4096 + j * 512),
                16, 0, 0);
        }
    };

    // ---- prologue ----
    {
        float4 xr[2][2];
        loadA(0, xr);
        stageB(0, 0);
        writeA(0, xr);
    }
    __syncthreads();

    // ---- 2-phase main loop: 16 K-steps of 64 ----
    #pragma unroll 2
    for (int step = 0; step < 16; ++step) {
        const int buf = step & 1;
        float4 xn[2][2];
        if (step < 15) {
            loadA((step + 1) * 64, xn);  // issue-early (T14)
            stageB(buf ^ 1, (step + 1) * 64);
        }

        half8 af[2][4], bf[2][4];
        #pragma unroll
        for (int kk = 0; kk < 2; ++kk) {
            #pragma unroll
            for (int mr = 0; mr < 4; ++mr) {
                const int row = mr * 16 + ln;
                const int ch = (kk * 4 + lg) ^ (ln & 7);
                af[kk][mr] = *reinterpret_cast<const half8*>(As + buf * 4096 + row * 64 + ch * 8);
            }
            #pragma unroll
            for (int nr = 0; nr < 4; ++nr) {
                const int n = w * 64 + nr * 16 + ln;
                const int ch = (kk * 4 + lg) ^ (ln & 7);
                bf[kk][nr] = *reinterpret_cast<const half8*>(Bs + buf * 16384 + n * 64 + ch * 8);
            }
        }
        #pragma unroll
        for (int kk = 0; kk < 2; ++kk)
            #pragma unroll
            for (int mr = 0; mr < 4; ++mr)
                #pragma unroll
                for (int nr = 0; nr < 4; ++nr)
                    acc[mr][nr] = __builtin_amdgcn_mfma_f32_16x16x32_f16(
                        af[kk][mr], bf[kk][nr], acc[mr][nr], 0, 0, 0);

        if (step < 15) writeA(buf ^ 1, xn);  // write-late (T14)
        __syncthreads();
    }

    // ---- epilogue ----
    if (t < 64) mkfs[t] = (float)mask[m0 + t];
    __syncthreads();

    float bias[4], a1c[4], a2c[4];
    #pragma unroll
    for (int nr = 0; nr < 4; ++nr) {
        const int n = w * 64 + nr * 16 + ln;
        bias[nr] = Wb[n];
        a1c[nr]  = aw[n];
        a2c[nr]  = aw[OUTD + n];
    }
    float sv1[4][4], sv2[4][4];
    #pragma unroll
    for (int i = 0; i < 4; ++i)
        #pragma unroll
        for (int r = 0; r < 4; ++r) { sv1[i][r] = 0.f; sv2[i][r] = 0.f; }

    #pragma unroll
    for (int mr = 0; mr < 4; ++mr)
        #pragma unroll
        for (int nr = 0; nr < 4; ++nr) {
            const int n = w * 64 + nr * 16 + ln;
            half4 hh, hl;
            #pragma unroll
            for (int rr = 0; rr < 4; ++rr) {
                const float hb = acc[mr][nr][rr] + bias[nr];
                sv1[mr][rr] += hb * a1c[nr];
                sv2[mr][rr] += hb * a2c[nr];
                const float hm = hb * mkfs[mr * 16 + lg * 4 + rr];
                const _Float16 hhi = (_Float16)hm;
                hh[rr] = hhi;
                hl[rr] = (_Float16)(hm - (float)hhi);
            }
            const int idx = n * 64 + ((mr * 16 + lg * 4) ^ ((n & 7) << 3));
            *reinterpret_cast<half4*>(Th + idx) = hh;
            *reinterpret_cast<half4*>(Tl + idx) = hl;
        }

    #pragma unroll
    for (int mr = 0; mr < 4; ++mr)
        #pragma unroll
        for (int rr = 0; rr < 4; ++rr) {
            float v1 = sv1[mr][rr], v2 = sv2[mr][rr];
            #pragma unroll
            for (int off = 1; off < 16; off <<= 1) {
                v1 += __shfl_xor(v1, off, 64);
                v2 += __shfl_xor(v2, off, 64);
            }
            if (ln == 0) {
                s1p[w * 64 + mr * 16 + lg * 4 + rr] = v1;
                s2p[w * 64 + mr * 16 + lg * 4 + rr] = v2;
            }
        }
    __syncthreads();

    if (t < 64) {
        s1[m0 + t] = s1p[t] + s1p[64 + t] + s1p[128 + t] + s1p[192 + t];
        s2[m0 + t] = s2p[t] + s2p[64 + t] + s2p[128 + t] + s2p[192 + t];
    }

    // coalesced HmT store: 4 o-rows x 128B contiguous per instruction
    const int bIdx = m0 >> 9;
    const int e0   = m0 & 511;
    #pragma unroll
    for (int r4 = 0; r4 < 16; ++r4) {
        const int o = w * 64 + r4 * 4 + lg;
        const int src = o * 64 + ((ln * 4) ^ ((o & 7) << 3));
        const half4 vh = *reinterpret_cast<const half4*>(Th + src);
        const half4 vl = *reinterpret_cast<const half4*>(Tl + src);
        const size_t goff = ((size_t)(bIdx * OUTD + o) << 9) + e0 + ln * 4;
        *reinterpret_cast<half4*>(&HmTh[goff]) = vh;
        *reinterpret_cast<half4*>(&HmTl[goff]) = vl;
    }
}

// ---------------- Kernel 2: out[b] = softmax(scores[b]) @ (H[b]*m), MFMA ----
__global__ __launch_bounds__(256, 2) void attn_mfma(
    const _Float16* __restrict__ HmTh, const _Float16* __restrict__ HmTl,
    const float* __restrict__ s1, const float* __restrict__ s2,
    const int* __restrict__ mask, const float* __restrict__ ab_ptr,
    float* __restrict__ Out)
{
    __shared__ float s2v[Ee];
    __shared__ float mkv[Ee];
    __shared__ float rowc[64];
    __shared__ float rmax[64];
    __shared__ int   rvv[64];
    __shared__ _Float16 Pl[2][64][32];
    __shared__ float Zp[64][4];
    __shared__ float zr[64];
    __shared__ float wmax[4];

    const int bid = blockIdx.x;
    const int b  = bid & 63;
    const int i0 = (bid >> 6) * 64;
    const int t  = threadIdx.x;
    const int w  = t >> 6, l = t & 63, ln = l & 15, lg = l >> 4;
    const float ab = ab_ptr[0];

    float lmax = -INFINITY;
    #pragma unroll
    for (int q = 0; q < 2; ++q) {
        const int j = t + q * 256;
        const float sv = s2[b * Ee + j];
        const float mv = (float)mask[b * Ee + j];
        s2v[j] = sv; mkv[j] = mv;
        if (mv > 0.f) lmax = fmaxf(lmax, sv);
    }
    #pragma unroll
    for (int off = 32; off; off >>= 1) lmax = fmaxf(lmax, __shfl_xor(lmax, off, 64));
    if (l == 0) wmax[w] = lmax;
    __syncthreads();
    const float s2max = fmaxf(fmaxf(wmax[0], wmax[1]), fmaxf(wmax[2], wmax[3]));
    const int anyvalid = (s2max > -1e37f) ? 1 : 0;
    if (t < 64) {
        const float c = s1[b * Ee + i0 + t] + ab;
        rowc[t] = c;
        const int mi = mask[b * Ee + i0 + t];
        rvv[t] = (mi != 0) & anyvalid;
        const float rm = c + s2max;
        rmax[t] = (rm >= 0.f) ? rm : LRELU * rm;
    }
    __syncthreads();

    const int pi = t >> 2;
    const int pj = (t & 3) * 8;
    const float prc = rowc[pi];
    const float prm = rmax[pi];
    const int   prv = rvv[pi];
    float zacc = 0.f;

    const size_t obase = (size_t)b * OUTD * Ee;
    const int o0 = w * 64;

    floatx4 acc[4][4];
    #pragma unroll
    for (int i = 0; i < 4; ++i)
        #pragma unroll
        for (int j = 0; j < 4; ++j)
            acc[i][j] = (floatx4)0.f;

    for (int ks = 0; ks < 16; ++ks) {
        const int k0  = ks * 32;
        const int buf = ks & 1;

        half8 ph;
        #pragma unroll
        for (int kk = 0; kk < 8; ++kk) {
            const int j = k0 + pj + kk;
            float pv;
            if (prv) {
                float sc = prc + s2v[j];
                sc = (sc >= 0.f) ? sc : LRELU * sc;
                pv = (mkv[j] > 0.f) ? __expf(sc - prm) : 0.f;
            } else {
                pv = 1.f;
            }
            const _Float16 hq = (_Float16)pv;
            ph[kk] = hq;
            zacc += (float)hq;
        }
        *reinterpret_cast<half8*>(&Pl[buf][pi][pj]) = ph;

        half8 bh[4], bl[4];
        #pragma unroll
        for (int ot = 0; ot < 4; ++ot) {
            const size_t ro = obase + (size_t)(o0 + ot * 16 + ln) * Ee + k0 + lg * 8;
            bh[ot] = *reinterpret_cast<const half8*>(&HmTh[ro]);
            bl[ot] = *reinterpret_cast<const half8*>(&HmTl[ro]);
        }
        __syncthreads();

        half8 af[4];
        #pragma unroll
        for (int mr = 0; mr < 4; ++mr)
            af[mr] = *reinterpret_cast<const half8*>(&Pl[buf][mr * 16 + ln][lg * 8]);
        #pragma unroll
        for (int mr = 0; mr < 4; ++mr)
            #pragma unroll
            for (int ot = 0; ot < 4; ++ot) {
                acc[mr][ot] = __builtin_amdgcn_mfma_f32_16x16x32_f16(
                    af[mr], bh[ot], acc[mr][ot], 0, 0, 0);
                acc[mr][ot] = __builtin_amdgcn_mfma_f32_16x16x32_f16(
                    af[mr], bl[ot], acc[mr][ot], 0, 0, 0);
            }
    }

    Zp[pi][t & 3] = zacc;
    __syncthreads();
    if (t < 64) {
        const float z = Zp[t][0] + Zp[t][1] + Zp[t][2] + Zp[t][3];
        zr[t] = 1.f / z;
    }
    __syncthreads();

    float* __restrict__ Ob = Out + ((size_t)b * Ee + i0) * OUTD;
    #pragma unroll
    for (int mr = 0; mr < 4; ++mr)
        #pragma unroll
        for (int rr = 0; rr < 4; ++rr) {
            const int i = mr * 16 + lg * 4 + rr;
            const float rzi = zr[i];
            #pragma unroll
            for (int ot = 0; ot < 4; ++ot)
                Ob[(size_t)i * OUTD + o0 + ot * 16 + ln] = acc[mr][ot][rr] * rzi;
        }
}

extern "C" void kernel_launch(void* const* d_in, const int* in_sizes, int n_in,
                              void* d_out, int out_size, void* d_ws, size_t ws_size,
                              hipStream_t stream) {
    const float* X    = (const float*)d_in[0];
    // d_in[1] = adj : unused by the reference (dead input)
    const int*   mask = (const int*)d_in[2];
    const float* Ww   = (const float*)d_in[3];
    const float* Wb   = (const float*)d_in[4];
    const float* aw   = (const float*)d_in[5];
    const float* ab   = (const float*)d_in[6];
    float* out = (float*)d_out;

    _Float16* HmTh = (_Float16*)d_ws;                     // 16 MB
    _Float16* HmTl = HmTh + (size_t)Bb * OUTD * Ee;       // 16 MB
    float* s1 = (float*)(HmTl + (size_t)Bb * OUTD * Ee);  // 128 KB
    float* s2 = s1 + Mrows;                               // 128 KB
    _Float16* Whf = (_Float16*)(s2 + Mrows);              // 512 KB

    wconv_kernel<<<OUTD * IND / (256 * 4), 256, 0, stream>>>(Ww, Whf);
    gemm_h_f16<<<Mrows / 64, 256, 0, stream>>>(X, Whf, Wb, aw, mask,
                                               HmTh, HmTl, s1, s2);
    attn_mfma<<<Bb * (Ee / 64), 256, 0, stream>>>(HmTh, HmTl, s1, s2, mask, ab, out);
}